// Round 8
// baseline (168.601 us; speedup 1.0000x reference)
//
#include <hip/hip_runtime.h>
#include <math.h>

#define FT_OUT 256
#define VFT 640
#define CAP 96        // per-row bucket capacity; Poisson(32) max ~56-60, 96 = +11 sigma
#define CPAD 16       // counter stride in ints (64 B)

typedef _Float16 half8_t __attribute__((ext_vector_type(8)));
typedef float    float8_t __attribute__((ext_vector_type(8)));

// ---- merged prep: blocks [0, nfill) fill slots (4 nnz x 2 sides per thread,
// 8 independent atomic chains for latency pipelining); rest build W2h ----
// W2h[col][o] = (half)(ft_w[o][col] + fft_w[o][col%640])
__global__ __launch_bounds__(256) void prep_k(
    const float* __restrict__ ft_w, const float* __restrict__ fft_w,
    _Float16* __restrict__ W2h, int ft_in,
    const int* __restrict__ stm, const int* __restrict__ nstm,
    const float* __restrict__ vals, int nnz,
    int* __restrict__ cnt_s, int* __restrict__ cnt_n,
    int2* __restrict__ slot_s, int2* __restrict__ slot_n, int nfill)
{
    int bx = (int)blockIdx.x;
    if (bx < nfill) {
        int k0 = (bx * 256 + threadIdx.x) * 4;
        if (k0 >= nnz) return;
        if (k0 + 4 <= nnz) {
            const int4 rs = *(const int4*)(stm + k0);
            const int4 cs = *(const int4*)(stm + nnz + k0);
            const int4 rn = *(const int4*)(nstm + k0);
            const int4 cn = *(const int4*)(nstm + nnz + k0);
            const int4 vv = *(const int4*)(vals + k0);  // raw bits
            int rsa[4] = {rs.x, rs.y, rs.z, rs.w}, csa[4] = {cs.x, cs.y, cs.z, cs.w};
            int rna[4] = {rn.x, rn.y, rn.z, rn.w}, cna[4] = {cn.x, cn.y, cn.z, cn.w};
            int va[4] = {vv.x, vv.y, vv.z, vv.w};
            int ps[4], pn[4];
#pragma unroll
            for (int e = 0; e < 4; e++) ps[e] = atomicAdd(&cnt_s[rsa[e] * CPAD], 1);
#pragma unroll
            for (int e = 0; e < 4; e++) pn[e] = atomicAdd(&cnt_n[rna[e] * CPAD], 1);
#pragma unroll
            for (int e = 0; e < 4; e++)
                if (ps[e] < CAP) slot_s[(size_t)rsa[e] * CAP + ps[e]] = make_int2(csa[e], va[e]);
#pragma unroll
            for (int e = 0; e < 4; e++)
                if (pn[e] < CAP) slot_n[(size_t)rna[e] * CAP + pn[e]] = make_int2(cna[e], va[e]);
        } else {
            for (int k = k0; k < nnz; k++) {
                int vb = __float_as_int(vals[k]);
                int r = stm[k], c = stm[nnz + k];
                int pos = atomicAdd(&cnt_s[r * CPAD], 1);
                if (pos < CAP) slot_s[(size_t)r * CAP + pos] = make_int2(c, vb);
                r = nstm[k]; c = nstm[nnz + k];
                pos = atomicAdd(&cnt_n[r * CPAD], 1);
                if (pos < CAP) slot_n[(size_t)r * CAP + pos] = make_int2(c, vb);
            }
        }
        return;
    }
    // build: pre-add ft+fft during load -> single LDS tile
    __shared__ float tile[64][65];  // [out][col], sum of ft+fft
    bx -= nfill;
    int cb = (bx >> 2) * 64;     // 640 col tiles
    int ob = (bx & 3) * 64;      // 4 out tiles
    int fvb = cb % VFT;          // 640 % 64 == 0 -> contiguous 64-col window
    int tc4 = threadIdx.x & 15, tr = threadIdx.x >> 4;
#pragma unroll
    for (int i = 0; i < 4; i++) {
        int o = i * 16 + tr;
        const float4 f = *(const float4*)(ft_w + (size_t)(ob + o) * ft_in + cb + tc4 * 4);
        const float4 g = *(const float4*)(fft_w + (size_t)(ob + o) * VFT + fvb + tc4 * 4);
        tile[o][tc4 * 4 + 0] = f.x + g.x; tile[o][tc4 * 4 + 1] = f.y + g.y;
        tile[o][tc4 * 4 + 2] = f.z + g.z; tile[o][tc4 * 4 + 3] = f.w + g.w;
    }
    __syncthreads();
    int g = threadIdx.x & 7, cl = threadIdx.x >> 3;
#pragma unroll
    for (int i = 0; i < 2; i++) {
        int c = i * 32 + cl, col = cb + c;
        half8_t h;
#pragma unroll
        for (int jj = 0; jj < 8; jj++) h[jj] = (_Float16)tile[g * 8 + jj][c];
        *(half8_t*)(W2h + (size_t)col * FT_OUT + ob + g * 8) = h;
    }
}

// ------- fused gather + clip + head + sigmoid: one wave per (row, side) -------
// Lane halves: lanes 0-31 process even slot entries, 32-63 odd; each lane loads
// half8 (16B) covering 8 outputs at chunk (lane&31). 8 entries (8 weight loads +
// 4 slot loads) in flight per main-loop iteration.
__global__ __launch_bounds__(256) void fused_k(const _Float16* __restrict__ W2h,
    const int* __restrict__ cnt_s, const int2* __restrict__ slot_s,
    const int* __restrict__ cnt_n, const int2* __restrict__ slot_n,
    const float* __restrict__ ft_b, const float* __restrict__ fft_b,
    const float* __restrict__ out_w, const float* __restrict__ out_b,
    float* __restrict__ out, int B) {
    int lane = threadIdx.x & 63;
    int wid  = threadIdx.x >> 6;            // 0..3
    int row  = blockIdx.x * 2 + (wid >> 1); // 2 rows per block
    int side = wid & 1;                     // 0 = stm, 1 = nstm
    int hi   = lane >> 5;                   // 0 or 1: which slot entry of a pair
    int sl   = lane & 31;                   // 8-output chunk index

    const int*  cnt  = side ? cnt_n : cnt_s;
    const int2* slot = (side ? slot_n : slot_s) + (size_t)row * CAP;
    int n = min(cnt[row * CPAD], CAP);

    float8_t acc;
#pragma unroll
    for (int k = 0; k < 8; k++) acc[k] = 0.f;
    if (hi == 0) {  // bias only once across the two halves
        const float4* fb = (const float4*)(ft_b + sl * 8);
        const float4* gb = (const float4*)(fft_b + sl * 8);
        float4 a0 = fb[0], a1 = fb[1], c0 = gb[0], c1 = gb[1];
        acc[0] = a0.x + c0.x; acc[1] = a0.y + c0.y; acc[2] = a0.z + c0.z; acc[3] = a0.w + c0.w;
        acc[4] = a1.x + c1.x; acc[5] = a1.y + c1.y; acc[6] = a1.z + c1.z; acc[7] = a1.w + c1.w;
    }

    // non-temporal 8B pair loads of a 16B slot pair (j even, 16B-aligned)
#define LOADPAIR(j, cc, vv)                                                         \
    {                                                                               \
        unsigned long long p0 =                                                     \
            __builtin_nontemporal_load((const unsigned long long*)(slot + (j)));    \
        unsigned long long p1 =                                                     \
            __builtin_nontemporal_load((const unsigned long long*)(slot + (j)) + 1);\
        unsigned long long pe = hi ? p1 : p0;                                       \
        cc = (int)(pe & 0xffffffffu);                                               \
        vv = __int_as_float((int)(pe >> 32));                                       \
    }
#define PROC(cc, vv)                                                                \
    {                                                                               \
        const half8_t w_ = *(const half8_t*)(W2h + ((size_t)(cc) << 8) + (sl << 3));\
        _Pragma("unroll")                                                           \
        for (int k = 0; k < 8; k++) acc[k] += (vv) * (float)w_[k];                  \
    }

    int j = 0;
    for (; j + 16 <= n; j += 16) {  // 8 entries in flight
        int c0, c1, c2, c3, c4, c5, c6, c7;
        float v0, v1, v2, v3, v4, v5, v6, v7;
        LOADPAIR(j,      c0, v0)
        LOADPAIR(j + 2,  c1, v1)
        LOADPAIR(j + 4,  c2, v2)
        LOADPAIR(j + 6,  c3, v3)
        LOADPAIR(j + 8,  c4, v4)
        LOADPAIR(j + 10, c5, v5)
        LOADPAIR(j + 12, c6, v6)
        LOADPAIR(j + 14, c7, v7)
        PROC(c0, v0) PROC(c1, v1) PROC(c2, v2) PROC(c3, v3)
        PROC(c4, v4) PROC(c5, v5) PROC(c6, v6) PROC(c7, v7)
    }
    for (; j + 2 <= n; j += 2) {
        int c0; float v0;
        LOADPAIR(j, c0, v0)
        PROC(c0, v0)
    }
    if (j < n) {  // odd tail: high half contributes zero via dummy col 0
        const int2 e = slot[j];
        int   c_ = hi ? 0 : e.x;
        float v_ = hi ? 0.f : __int_as_float(e.y);
        PROC(c_, v_)
    }
#undef PROC
#undef LOADPAIR

    // combine the two lane-halves (lane l and l^32 own the same 8 outputs), clip
#pragma unroll
    for (int k = 0; k < 8; k++) {
        float o = __shfl_xor(acc[k], 32, 64);
        acc[k] = fminf(fmaxf(acc[k] + o, 0.f), 1.f);
    }

    const float4* ow = (const float4*)(out_w + side * FT_OUT + sl * 8);
    const float4 w0 = ow[0], w1 = ow[1];
    float p = acc[0] * w0.x + acc[1] * w0.y + acc[2] * w0.z + acc[3] * w0.w
            + acc[4] * w1.x + acc[5] * w1.y + acc[6] * w1.z + acc[7] * w1.w;
#pragma unroll
    for (int m = 32; m >= 1; m >>= 1) p += __shfl_xor(p, m, 64);
    p *= 0.5f;  // both halves duplicated the per-chunk partials

    __shared__ float part[4];
    if (lane == 0) part[wid] = p;
    __syncthreads();
    if (threadIdx.x < 2) {
        float q = part[threadIdx.x * 2] + part[threadIdx.x * 2 + 1] + out_b[0];
        out[blockIdx.x * 2 + threadIdx.x] = 1.f / (1.f + __expf(-q));
    }
}

extern "C" void kernel_launch(void* const* d_in, const int* in_sizes, int n_in,
                              void* d_out, int out_size, void* d_ws, size_t ws_size,
                              hipStream_t stream) {
    const int*   stm    = (const int*)d_in[0];   // [2, NNZ]: rows then cols
    const int*   nstm   = (const int*)d_in[1];
    const float* values = (const float*)d_in[2];
    const float* ft_w   = (const float*)d_in[4];
    const float* ft_b   = (const float*)d_in[5];
    const float* fft_w  = (const float*)d_in[6];
    const float* fft_b  = (const float*)d_in[7];
    const float* out_w  = (const float*)d_in[8];
    const float* out_b  = (const float*)d_in[9];
    float* out = (float*)d_out;

    int B = out_size;                 // 8192
    int nnz = in_sizes[0] / 2;        // 262144
    int ft_in = in_sizes[4] / FT_OUT; // 40960

    // workspace layout (16B-aligned pieces)
    _Float16* W2h  = (_Float16*)d_ws;                          // ft_in*256 halfs (20 MB)
    int2*  slot_s  = (int2*)(W2h + (size_t)ft_in * FT_OUT);    // B*CAP entries (6 MB)
    int2*  slot_n  = slot_s + (size_t)B * CAP;                 // 6 MB
    int*   cnt_s   = (int*)(slot_n + (size_t)B * CAP);         // B*CPAD (512 KB)
    int*   cnt_n   = cnt_s + (size_t)B * CPAD;                 // B*CPAD

    int nfill  = (nnz / 4 + 255) / 256;                        // 256
    int nbuild = (ft_in / 64) * (FT_OUT / 64);                 // 2560

    hipMemsetAsync(cnt_s, 0, 2 * (size_t)B * CPAD * sizeof(int), stream);
    prep_k<<<nfill + nbuild, 256, 0, stream>>>(ft_w, fft_w, W2h, ft_in,
                                               stm, nstm, values, nnz,
                                               cnt_s, cnt_n, slot_s, slot_n, nfill);
    fused_k<<<B / 2, 256, 0, stream>>>(W2h, cnt_s, slot_s, cnt_n, slot_n,
                                       ft_b, fft_b, out_w, out_b, out, B);
}